// Round 13
// baseline (277.495 us; speedup 1.0000x reference)
//
#include <hip/hip_runtime.h>
#include <hip/hip_bf16.h>
#include <math.h>

#define Bq 4
#define Sq 512
#define Hq 512
#define NHq 8
#define Tq 3
#define DTSq 170
#define BSq 2048
#define NLUT 512
#define MAGMAXf 5.6304994f

typedef float f32x4 __attribute__((ext_vector_type(4)));
typedef __bf16 bf16x4 __attribute__((ext_vector_type(4)));
typedef __bf16 bf16x8 __attribute__((ext_vector_type(8)));

__device__ __forceinline__ float gelu_f(float x){
  return 0.5f * x * (1.0f + erff(x * 0.70710678118654752f));
}

__device__ __forceinline__ void gload16(const void* g, void* l){
  __builtin_amdgcn_global_load_lds((const __attribute__((address_space(1))) void*)g,
                                   (__attribute__((address_space(3))) void*)l, 16, 0, 0);
}

__device__ __forceinline__ float waveReduceSum(float v){
  #pragma unroll
  for (int off = 32; off > 0; off >>= 1) v += __shfl_xor(v, off);
  return v;
}

__device__ __forceinline__ float blockReduce(float v, float* red){
  int tid = threadIdx.x;
  __syncthreads();
  red[tid] = v; __syncthreads();
  for (int s = 128; s > 0; s >>= 1){
    if (tid < s) red[tid] += red[tid + s];
    __syncthreads();
  }
  return red[0];
}

// ---------------- merged prep: x->bf16 | weight T-convert | mask LUT --------
struct CvtEnt { const float* W; __bf16* WT; int ldw, ldt, ntn, start; };
struct CvtArgs { CvtEnt e[12]; };

__global__ __launch_bounds__(256) void prep_all(
    const float* __restrict__ x, __bf16* __restrict__ xb,
    CvtArgs a,
    const float* __restrict__ encW, const float* __restrict__ encB,
    const float* __restrict__ g, const float* __restrict__ be,
    float* __restrict__ lut)
{
  __shared__ float T[64][65];
  __shared__ float red[256];
  __shared__ float sw0[DTSq], sw1[DTSq], sbc[DTSq], sg[DTSq], sbe[DTSq];
  __shared__ float sS[6];
  int bid = blockIdx.x, tid = threadIdx.x;

  if (bid < 1024){                                  // cvt_bf: x -> XB
    int idx = (bid * 256 + tid) * 4;
    float4 v = *(const float4*)&x[idx];
    bf16x4 r; r[0]=(__bf16)v.x; r[1]=(__bf16)v.y; r[2]=(__bf16)v.z; r[3]=(__bf16)v.w;
    *(bf16x4*)&xb[idx] = r;
    return;
  }
  if (bid < 1024 + 1792){                           // weight transpose-convert
    int wb = bid - 1024;
    int i = 0;
    #pragma unroll
    for (int k = 1; k < 12; ++k) if (wb >= a.e[k].start) i = k;
    const float* W = a.e[i].W;
    __bf16* WT = a.e[i].WT;
    int ldw = a.e[i].ldw, ldt = a.e[i].ldt;
    int local = wb - a.e[i].start;
    int tn = local % a.e[i].ntn, tk = local / a.e[i].ntn;
    int n0 = tn * 64, k0 = tk * 64;
    #pragma unroll
    for (int q = 0; q < 16; ++q){
      int lin = q * 256 + tid;
      int r = lin >> 6, c = lin & 63;
      T[r][c] = W[(size_t)(k0 + r) * ldw + n0 + c];
    }
    __syncthreads();
    #pragma unroll
    for (int q = 0; q < 16; ++q){
      int lin = q * 256 + tid;
      int n = lin >> 6, k = lin & 63;
      WT[(size_t)(n0 + n) * ldt + k0 + k] = (__bf16)T[k][n];
    }
    return;
  }
  // mask LUT build (18 blocks): local = td*2 + echunk
  int local = bid - (1024 + 1792);
  int td = local >> 1, echunk = local & 1;
  int t = td / 3, dsel = td % 3;
  float d = (float)(dsel - 1);
  const float* W0 = encW + t * 2 * DTSq;
  const float* W1 = W0 + DTSq;
  const float* Bv = encB + t * DTSq;
  float w0 = (tid < DTSq) ? W0[tid] : 0.f;
  float w1 = (tid < DTSq) ? W1[tid] : 0.f;
  float bv = (tid < DTSq) ? Bv[tid] : 0.f;
  const float invD = 1.0f / (float)DTSq;
  float m0 = blockReduce(w0, red) * invD;
  float m1 = blockReduce(w1, red) * invD;
  float mb = blockReduce(bv, red) * invD;
  float c0 = (tid < DTSq) ? (w0 - m0) : 0.f;
  float c1 = (tid < DTSq) ? (w1 - m1) : 0.f;
  float cb = (tid < DTSq) ? (bv - mb) : 0.f;
  if (tid < DTSq){
    sw0[tid] = c0; sw1[tid] = c1; sbc[tid] = cb;
    sg[tid] = g[t * DTSq + tid]; sbe[tid] = be[t * DTSq + tid];
  }
  float pa = blockReduce(c0 * c0, red) * invD;
  float pb = blockReduce(c1 * c1, red) * invD;
  float pc = blockReduce(c0 * c1, red) * invD;
  float pd = blockReduce(c0 * cb, red) * invD;
  float pe = blockReduce(c1 * cb, red) * invD;
  float pf = blockReduce(cb * cb, red) * invD;
  if (tid == 0){ sS[0]=pa; sS[1]=pb; sS[2]=pc; sS[3]=pd; sS[4]=pe; sS[5]=pf; }
  __syncthreads();
  float A = sS[0], Bs = sS[1], Cs = sS[2], Ds = sS[3], Es = sS[4], Fs = sS[5];
  int e = echunk * 256 + tid;
  float tscale = (t == 0) ? 1.f : ((t == 1) ? 0.1f : 0.01f);
  float m = (MAGMAXf / (float)(NLUT - 1)) * (float)e * tscale;
  float var = fabsf(d) * A + m * m * Bs + Fs + 2.f * (d * m * Cs + d * Ds + m * Es);
  float rs = rsqrtf(var + 1e-5f);
  float sum = 0.f;
  for (int c = 0; c < DTSq; ++c){
    float ee = fmaf(m, sw1[c], fmaf(d, sw0[c], sbc[c]));
    float n = fmaf(ee * rs, sg[c], sbe[c]);
    sum += n * 0.5f * (1.0f + erff(n * 0.70710678118654752f));
  }
  lut[td * NLUT + e] = sum * (1.0f / (float)DTSq);
}

// ------ pipelined bf16 MFMA GEMM (counted vmcnt, 2 barriers; BK templated) ---
template<int BM, int BN, int BK>
__global__ __launch_bounds__(256) void gemm_pipe(
    const __bf16* __restrict__ A, int lda, size_t sAz,
    const __bf16* __restrict__ BT, int ldb, size_t sBz,
    const float* __restrict__ bias, int sBiasz,
    float* __restrict__ C32, __bf16* __restrict__ C16, int ldc, size_t sCz,
    int K, int act)
{
  constexpr int MF = BM / 32;
  constexpr int NF = BN / 32;
  constexpr int ROWB = BK * 2;                 // bytes per LDS row
  constexpr int SWZM = (BK == 64) ? 7 : 15;    // swizzle row mask
  constexpr int ALOADS = BM * ROWB / 4096;
  constexpr int BLOADS = BN * ROWB / 4096;
  constexpr int LOADS = ALOADS + BLOADS;
  constexpr int ABYTES = BM * ROWB;
  constexpr int BBYTES = BN * ROWB;
  __shared__ __bf16 lds[(2 * (ABYTES + BBYTES)) / 2];
  int tid = threadIdx.x;

  int gx = gridDim.x, nwg = gx * gridDim.y;
  int lin = blockIdx.x + gx * blockIdx.y;
  int q8 = nwg >> 3;
  int swz = (lin & 7) * q8 + (lin >> 3);
  int bx = swz % gx, by = swz / gx;

  int z = blockIdx.z;
  A  += (size_t)z * sAz;
  BT += (size_t)z * sBz;
  const float* bz = bias ? bias + (size_t)z * sBiasz : nullptr;
  size_t cbase = (size_t)z * sCz;
  int brow = by * BM, bcol = bx * BN;

  int lane = tid & 63, w = tid >> 6;
  int wr = (w >> 1) * (BM / 2), wc = (w & 1) * (BN / 2);
  int lr = lane & 15, lg = lane >> 4;

  f32x4 acc[MF][NF];
  #pragma unroll
  for (int m = 0; m < MF; ++m)
    #pragma unroll
    for (int n = 0; n < NF; ++n) acc[m][n] = (f32x4){0.f, 0.f, 0.f, 0.f};

  char* lbase = (char*)lds;

  auto stage = [&](int buf, int ko){
    char* ab = lbase + buf * (ABYTES + BBYTES);
    #pragma unroll
    for (int qq = 0; qq < ALOADS; ++qq){
      int byte = (qq * 256 + tid) * 16;
      int row = byte / ROWB, col = byte % ROWB;
      int src = col ^ ((row & SWZM) << 4);
      gload16(&A[(size_t)(brow + row) * lda + ko + (src >> 1)], ab + byte);
    }
    char* bb = ab + ABYTES;
    #pragma unroll
    for (int qq = 0; qq < BLOADS; ++qq){
      int byte = (qq * 256 + tid) * 16;
      int row = byte / ROWB, col = byte % ROWB;
      int src = col ^ ((row & SWZM) << 4);
      gload16(&BT[(size_t)(bcol + row) * ldb + ko + (src >> 1)], bb + byte);
    }
  };

  stage(0, 0);
  int nk = K / BK;
  for (int kt = 0; kt < nk; ++kt){
    int cur = kt & 1;
    if (kt + 1 < nk){
      stage(cur ^ 1, (kt + 1) * BK);
      if constexpr (LOADS == 3)      asm volatile("s_waitcnt vmcnt(3)" ::: "memory");
      else if constexpr (LOADS == 4) asm volatile("s_waitcnt vmcnt(4)" ::: "memory");
      else                           asm volatile("s_waitcnt vmcnt(6)" ::: "memory");
    } else {
      asm volatile("s_waitcnt vmcnt(0)" ::: "memory");
    }
    __builtin_amdgcn_s_barrier();
    __builtin_amdgcn_sched_barrier(0);
    char* ab = lbase + cur * (ABYTES + BBYTES);
    char* bb = ab + ABYTES;
    #pragma unroll
    for (int s = 0; s < BK / 32; ++s){
      bf16x8 af[MF], bfr[NF];
      #pragma unroll
      for (int m = 0; m < MF; ++m){
        int row = wr + m * 16 + lr;
        int col = (s * 64 + lg * 16) ^ ((row & SWZM) << 4);
        af[m] = *(const bf16x8*)(ab + row * ROWB + col);
      }
      #pragma unroll
      for (int n = 0; n < NF; ++n){
        int row = wc + n * 16 + lr;
        int col = (s * 64 + lg * 16) ^ ((row & SWZM) << 4);
        bfr[n] = *(const bf16x8*)(bb + row * ROWB + col);
      }
      #pragma unroll
      for (int m = 0; m < MF; ++m)
        #pragma unroll
        for (int n = 0; n < NF; ++n)
          acc[m][n] = __builtin_amdgcn_mfma_f32_16x16x32_bf16(af[m], bfr[n], acc[m][n], 0, 0, 0);
    }
    asm volatile("" ::: "memory");
    __builtin_amdgcn_s_barrier();
  }

  #pragma unroll
  for (int m = 0; m < MF; ++m){
    #pragma unroll
    for (int n = 0; n < NF; ++n){
      int col = bcol + wc + n * 16 + lr;
      float bv = bz ? bz[col] : 0.f;
      #pragma unroll
      for (int j = 0; j < 4; ++j){
        int row = brow + wr + m * 16 + lg * 4 + j;
        float v = acc[m][n][j] + bv;
        if (act) v = gelu_f(v);
        size_t idx = cbase + (size_t)row * ldc + col;
        if (C32) C32[idx] = v;
        if (C16) C16[idx] = (__bf16)v;
      }
    }
  }
}

// -------- flash attention v5: mask computed in-kernel from LDS LUT -----------
// LDS: [0,32K) K/V dbuf | [32K,40K) Ps | HM: [40K,42K) ts row | [42K,48K) lut
template<bool HM>
__global__ __launch_bounds__(256) void flash_attn(
    const __bf16* __restrict__ qkv, size_t sQz,   // [2048][1536]
    const __bf16* __restrict__ vt,  size_t sVz,   // [32][64][512]
    const float* __restrict__ tsg,                // [4][512] timestamps
    const float* __restrict__ lutg,               // [9][NLUT] f32
    __bf16* __restrict__ ctx, size_t sCz)         // [2048][512]
{
  int t = blockIdx.z;
  qkv += (size_t)t * sQz;
  vt  += (size_t)t * sVz;
  ctx += (size_t)t * sCz;

  int lin = blockIdx.x + (blockIdx.y << 3);
  int swz = (lin & 7) * 32 + (lin >> 3);
  int io = (swz & 7) * 64;
  int bh = swz >> 3;
  int b = bh >> 3, h = bh & 7;

  constexpr int TB = 8192;
  constexpr int BUFB = 2 * TB;
  __shared__ char lds[2 * BUFB + TB + (HM ? 8192 : 0)];
  char* lb = lds;
  char* psb = lb + 2 * BUFB;                     // Ps region (8 KB)
  float* tsL  = (float*)(lb + 2 * BUFB + TB);          // 512 f32
  float* lutL = (float*)(lb + 2 * BUFB + TB + 2048);   // 3*NLUT f32
  int tid = threadIdx.x, lane = tid & 63, w = tid >> 6;
  int lr = lane & 15, lg = lane >> 4;

  const __bf16* qrow = &qkv[(size_t)(b * Sq + io + w * 16 + lr) * 1536 + h * 64];
  bf16x8 q0 = *(const bf16x8*)&qrow[lg * 8];
  bf16x8 q1 = *(const bf16x8*)&qrow[32 + lg * 8];

  // prologue DMA: ts row (128 chunks) + lut 3 rows (384 chunks) — wave-uniform split
  if constexpr (HM){
    const float* tsrow = tsg + b * Sq;
    const float* lrow  = lutg + t * 3 * NLUT;
    #pragma unroll
    for (int qq = 0; qq < 2; ++qq){
      int c = qq * 256 + tid;
      if (c < 128) gload16(tsrow + c * 4, (char*)tsL + c * 16);
      else         gload16(lrow + (c - 128) * 4, (char*)lutL + (c - 128) * 16);
    }
  }

  auto stage = [&](int buf, int jo){
    char* kb = lb + buf * BUFB;
    #pragma unroll
    for (int qq = 0; qq < 2; ++qq){
      int byte = (qq * 256 + tid) * 16;
      int row = byte >> 7;
      int src = (byte & 127) ^ ((row & 7) << 4);
      gload16(&qkv[(size_t)(b * Sq + jo + row) * 1536 + 512 + h * 64 + (src >> 1)], kb + byte);
    }
    char* vb = kb + TB;
    #pragma unroll
    for (int qq = 0; qq < 2; ++qq){
      int byte = (qq * 256 + tid) * 16;
      int row = byte >> 7;
      int src = (byte & 127) ^ ((row & 7) << 4);
      gload16(&vt[((size_t)bh * 64 + row) * Sq + jo + (src >> 1)], vb + byte);
    }
  };

  f32x4 o[4];
  #pragma unroll
  for (int n = 0; n < 4; ++n) o[n] = (f32x4){0.f, 0.f, 0.f, 0.f};
  float mrow[4] = {-1e30f, -1e30f, -1e30f, -1e30f};
  float lrow[4] = {0.f, 0.f, 0.f, 0.f};

  stage(0, 0);
  #pragma unroll
  for (int kt = 0; kt < 8; ++kt){
    int cur = kt & 1;
    int jo = kt << 6;

    if (kt + 1 < 8){
      stage(cur ^ 1, (kt + 1) << 6);
      asm volatile("s_waitcnt vmcnt(4)" ::: "memory");   // drains prologue + cur stage
    } else {
      asm volatile("s_waitcnt vmcnt(0)" ::: "memory");
    }
    __builtin_amdgcn_s_barrier();
    __builtin_amdgcn_sched_barrier(0);

    char* kb = lb + cur * BUFB;
    char* vb = kb + TB;

    // QK^T
    f32x4 s4[4];
    #pragma unroll
    for (int n = 0; n < 4; ++n) s4[n] = (f32x4){0.f, 0.f, 0.f, 0.f};
    __builtin_amdgcn_s_setprio(1);
    #pragma unroll
    for (int s = 0; s < 2; ++s){
      bf16x8 aq = s ? q1 : q0;
      #pragma unroll
      for (int n = 0; n < 4; ++n){
        int row = n * 16 + lr;
        int colb = (s * 64 + lg * 16) ^ ((row & 7) << 4);
        bf16x8 bk = *(const bf16x8*)(kb + row * 128 + colb);
        s4[n] = __builtin_amdgcn_mfma_f32_16x16x32_bf16(aq, bk, s4[n], 0, 0, 0);
      }
    }
    __builtin_amdgcn_s_setprio(0);

    float sv[4][4];
    if constexpr (HM){
      float tsj[4], tsi[4];
      #pragma unroll
      for (int n = 0; n < 4; ++n) tsj[n] = tsL[jo + n * 16 + lr];
      #pragma unroll
      for (int reg = 0; reg < 4; ++reg) tsi[reg] = tsL[io + w * 16 + lg * 4 + reg];
      #pragma unroll
      for (int n = 0; n < 4; ++n){
        #pragma unroll
        for (int reg = 0; reg < 4; ++reg){
          float dt = tsi[reg] - tsj[n];
          int dsel = (dt > 0.f) ? 2 : ((dt < 0.f) ? 0 : 1);
          float mag = log1pf(fabsf(dt) * (1.0f / 3600.0f));
          float u = mag * ((float)(NLUT - 1) / MAGMAXf);
          int i0 = (int)u; if (i0 > NLUT - 2) i0 = NLUT - 2;
          float f = u - (float)i0;
          const float* lp = lutL + dsel * NLUT + i0;
          float mv = lp[0] + f * (lp[1] - lp[0]);
          sv[n][reg] = s4[n][reg] * 0.125f + mv;
        }
      }
    } else {
      #pragma unroll
      for (int n = 0; n < 4; ++n)
        #pragma unroll
        for (int reg = 0; reg < 4; ++reg)
          sv[n][reg] = s4[n][reg] * 0.125f;
    }

    // online softmax with defer-max (THR=8)
    #pragma unroll
    for (int reg = 0; reg < 4; ++reg){
      float pmax = fmaxf(fmaxf(sv[0][reg], sv[1][reg]), fmaxf(sv[2][reg], sv[3][reg]));
      #pragma unroll
      for (int off = 1; off < 16; off <<= 1) pmax = fmaxf(pmax, __shfl_xor(pmax, off));
      if (pmax > mrow[reg] + 8.0f){
        float corr = __expf(mrow[reg] - pmax);
        mrow[reg] = pmax;
        lrow[reg] *= corr;
        #pragma unroll
        for (int n = 0; n < 4; ++n) o[n][reg] *= corr;
      }
      float rs = 0.f;
      #pragma unroll
      for (int n = 0; n < 4; ++n){
        float p = __expf(sv[n][reg] - mrow[reg]);
        sv[n][reg] = p;
        rs += p;
      }
      #pragma unroll
      for (int off = 1; off < 16; off <<= 1) rs += __shfl_xor(rs, off);
      lrow[reg] += rs;
    }

    // P -> Ps region (per-wave 16-row slice), then PV
    #pragma unroll
    for (int n = 0; n < 4; ++n)
      #pragma unroll
      for (int reg = 0; reg < 4; ++reg){
        int row = w * 16 + lg * 4 + reg;
        int off = ((n * 16 + lr) * 2) ^ ((row & 7) << 4);
        *(__bf16*)(psb + row * 128 + off) = (__bf16)sv[n][reg];
      }
    __builtin_amdgcn_s_setprio(1);
    #pragma unroll
    for (int s = 0; s < 2; ++s){
      int arow = w * 16 + lr;
      int acol = (s * 64 + lg * 16) ^ ((arow & 7) << 4);
      bf16x8 ap = *(const bf16x8*)(psb + arow * 128 + acol);
      #pragma unroll
      for (int n = 0; n < 4; ++n){
        int row = n * 16 + lr;
        int colb = (s * 64 + lg * 16) ^ ((row & 7) << 4);
        bf16x8 bv = *(const bf16x8*)(vb + row * 128 + colb);
        o[n] = __builtin_amdgcn_mfma_f32_16x16x32_bf16(ap, bv, o[n], 0, 0, 0);
      }
    }
    __builtin_amdgcn_s_setprio(0);

    asm volatile("" ::: "memory");
    __builtin_amdgcn_s_barrier();                 // protect buf reuse by next stage()
  }

  #pragma unroll
  for (int reg = 0; reg < 4; ++reg){
    float inv = 1.0f / lrow[reg];
    int row = b * Sq + io + w * 16 + lg * 4 + reg;
    #pragma unroll
    for (int n = 0; n < 4; ++n)
      ctx[(size_t)row * Hq + h * 64 + n * 16 + lr] = (__bf16)(o[n][reg] * inv);
  }
}

// ---------------- row LayerNorm (+residual), dual-dtype out ------------------
__global__ __launch_bounds__(256) void ln_rows(const float* __restrict__ in,
                                               const float* __restrict__ res,
                                               const float* __restrict__ g,
                                               const float* __restrict__ bb,
                                               float* __restrict__ out32,
                                               __bf16* __restrict__ out16,
                                               int do_gelu){
  int row = blockIdx.x * 4 + (threadIdx.x >> 6);
  int lane = threadIdx.x & 63;
  const float* ir = in + (size_t)row * Hq;
  const float* rr = res ? res + (size_t)row * Hq : nullptr;
  float x[8]; float s = 0.f, sq = 0.f;
  #pragma unroll
  for (int k = 0; k < 8; ++k){
    int c = lane + 64 * k;
    float v = ir[c];
    if (rr) v += rr[c];
    x[k] = v; s += v; sq += v * v;
  }
  s = waveReduceSum(s); sq = waveReduceSum(sq);
  float mean = s * (1.0f / Hq);
  float var = fmaxf(sq * (1.0f / Hq) - mean * mean, 0.f);
  float rstd = rsqrtf(var + 1e-5f);
  #pragma unroll
  for (int k = 0; k < 8; ++k){
    int c = lane + 64 * k;
    float y = (x[k] - mean) * rstd * g[c] + bb[c];
    if (do_gelu) y = gelu_f(y);
    if (out32) out32[(size_t)row * Hq + c] = y;
    if (out16) out16[(size_t)row * Hq + c] = (__bf16)y;
  }
}

// ------- fused: LN + gelu + mixer2 + softmax over T + weighted combine -------
__global__ __launch_bounds__(256) void ln_mixer_weighted(const float* __restrict__ in,
                                                         const float* __restrict__ g,
                                                         const float* __restrict__ bb,
                                                         const float* __restrict__ W2,
                                                         const float* __restrict__ b2,
                                                         const __bf16* __restrict__ comb,
                                                         float* __restrict__ out32,
                                                         __bf16* __restrict__ out16){
  int row = blockIdx.x * 4 + (threadIdx.x >> 6);
  int lane = threadIdx.x & 63;
  const float* ir = in + (size_t)row * Hq;
  float x[8]; float s = 0.f, sq = 0.f;
  #pragma unroll
  for (int k = 0; k < 8; ++k){
    int c = lane + 64 * k;
    float v = ir[c];
    x[k] = v; s += v; sq += v * v;
  }
  s = waveReduceSum(s); sq = waveReduceSum(sq);
  float mean = s * (1.0f / Hq);
  float var = fmaxf(sq * (1.0f / Hq) - mean * mean, 0.f);
  float rstd = rsqrtf(var + 1e-5f);
  float a0 = 0.f, a1 = 0.f, a2 = 0.f;
  #pragma unroll
  for (int k = 0; k < 8; ++k){
    int c = lane + 64 * k;
    float y = gelu_f((x[k] - mean) * rstd * g[c] + bb[c]);
    const float* wv = W2 + c * 3;
    a0 = fmaf(y, wv[0], a0); a1 = fmaf(y, wv[1], a1); a2 = fmaf(y, wv[2], a2);
  }
  a0 = waveReduceSum(a0) + b2[0];
  a1 = waveReduceSum(a1) + b2[1];
  a2 = waveReduceSum(a2) + b2[2];
  float mx = fmaxf(a0, fmaxf(a1, a2));
  float e0 = __expf(a0 - mx), e1 = __expf(a1 - mx), e2 = __expf(a2 - mx);
  float inv = 1.0f / (e0 + e1 + e2);
  float m0 = e0 * inv, m1 = e1 * inv, m2 = e2 * inv;
  const __bf16* cr = comb + (size_t)row * 1536;
  #pragma unroll
  for (int k = 0; k < 8; ++k){
    int c = lane + 64 * k;
    float v = m0 * (float)cr[c] + m1 * (float)cr[512 + c] + m2 * (float)cr[1024 + c];
    out32[(size_t)row * Hq + c] = v;
    out16[(size_t)row * Hq + c] = (__bf16)v;
  }
}

// ---------------- V transpose per head (z-batched over t) --------------------
__global__ __launch_bounds__(256) void transpose_v(const __bf16* __restrict__ qkv, size_t sQz,
                                                   __bf16* __restrict__ vt, size_t sVz){
  int t = blockIdx.z;
  qkv += (size_t)t * sQz;
  vt  += (size_t)t * sVz;
  int bh = blockIdx.y, b = bh >> 3, h = bh & 7;
  int so = blockIdx.x * 64;
  __shared__ __bf16 T[64][72];
  int tid = threadIdx.x;
  #pragma unroll
  for (int q = 0; q < 16; ++q){
    int lin = q * 256 + tid;
    int r = lin >> 6, c = lin & 63;
    T[r][c] = qkv[(size_t)(b * Sq + so + r) * 1536 + 1024 + h * 64 + c];
  }
  __syncthreads();
  #pragma unroll
  for (int q = 0; q < 16; ++q){
    int lin = q * 256 + tid;
    int d = lin >> 6, s = lin & 63;
    vt[((size_t)bh * 64 + d) * Sq + so + s] = T[s][d];
  }
}

extern "C" void kernel_launch(void* const* d_in, const int* in_sizes, int n_in,
                              void* d_out, int out_size, void* d_ws, size_t ws_size,
                              hipStream_t stream){
  const float* x         = (const float*)d_in[0];
  const float* ts        = (const float*)d_in[1];
  const float* enc_W     = (const float*)d_in[2];
  const float* enc_b     = (const float*)d_in[3];
  const float* enc_ln_g  = (const float*)d_in[4];
  const float* enc_ln_b  = (const float*)d_in[5];
  const float* qkv_W     = (const float*)d_in[6];
  const float* qkv_b     = (const float*)d_in[7];
  const float* aout_W    = (const float*)d_in[8];
  const float* aout_b    = (const float*)d_in[9];
  const float* mx_W1     = (const float*)d_in[10];
  const float* mx_b1     = (const float*)d_in[11];
  const float* mx_ln_g   = (const float*)d_in[12];
  const float* mx_ln_b   = (const float*)d_in[13];
  const float* mx_W2     = (const float*)d_in[14];
  const float* mx_b2     = (const float*)d_in[15];
  const float* el_qkv_W  = (const float*)d_in[16];
  const float* el_qkv_b  = (const float*)d_in[17];
  const float* el_out_W  = (const float*)d_in[18];
  const float* el_out_b  = (const float*)d_in[19];
  const float* el_ln1_g  = (const float*)d_in[20];
  const float* el_ln1_b  = (const float*)d_in[21];
  const float* el_ff_W1  = (const float*)d_in[22];
  const float* el_ff_b1  = (const float*)d_in[23];
  const float* el_ff_W2  = (const float*)d_in[24];
  const float* el_ff_b2  = (const float*)d_in[25];
  const float* el_ln2_g  = (const float*)d_in[26];
  const float* el_ln2_b  = (const float*)d_in[27];
  const float* op_W      = (const float*)d_in[28];
  const float* op_b      = (const float*)d_in[29];
  const float* op_ln_g   = (const float*)d_in[30];
  const float* op_ln_b   = (const float*)d_in[31];

  float* ws = (float*)d_ws;
  size_t o = 0;
  float*  LUTB   = ws + o;            o += 9 * NLUT;          // 16B-aligned (o=0)
  __bf16* XB     = (__bf16*)(ws + o); o += 524288;            // [2048][512]
  __bf16* qkvT   = (__bf16*)(ws + o); o += 1179648;           // [3][1536][512]
  __bf16* aoutT  = (__bf16*)(ws + o); o += 393216;            // [3][512][512]
  __bf16* mx1T   = (__bf16*)(ws + o); o += 393216;            // [512][1536]
  __bf16* elqkvT = (__bf16*)(ws + o); o += 393216;            // [1536][512]
  __bf16* eloutT = (__bf16*)(ws + o); o += 131072;            // [512][512]
  __bf16* ff1T   = (__bf16*)(ws + o); o += 524288;            // [2048][512]
  __bf16* ff2T   = (__bf16*)(ws + o); o += 524288;            // [512][2048]
  __bf16* opT    = (__bf16*)(ws + o); o += 131072;            // [512][512]
  __bf16* QKVb   = (__bf16*)(ws + o); o += 4718592;           // [3][2048][1536]
  __bf16* VTb    = (__bf16*)(ws + o); o += 1572864;           // [3][32][64][512]
  __bf16* FFBb   = (__bf16*)(ws + o); o += 2097152;           // [2048][2048]
  __bf16* CTXb   = (__bf16*)(ws + o); o += 1572864;           // [3][2048][512]
  __bf16* COMBb  = (__bf16*)(ws + o); o += 1572864;           // [2048][1536]
  float*  MBUF   = ws + o;            o += 1048576;           // mixer1 out, also OPO
  float*  WEI    = ws + o;            o += 1048576;
  __bf16* WEIb   = (__bf16*)(ws + o); o += 524288;
  float*  SA     = ws + o;            o += 1048576;
  float*  H1     = ws + o;            o += 1048576;
  __bf16* H1b    = (__bf16*)(ws + o); o += 524288;
  float*  H2     = ws + o;            o += 1048576;
  __bf16* H2b    = (__bf16*)(ws + o); o += 524288;
  float*  OPO    = MBUF;

  // 0+1. merged prep: x->bf16, weight transposes, mask LUT
  {
    CvtArgs ca;
    for (int t = 0; t < 3; ++t)
      ca.e[t] = {qkv_W + (size_t)t * 512 * 1536, qkvT + (size_t)t * 1536 * 512, 1536, 512, 24, 192 * t};
    for (int t = 0; t < 3; ++t)
      ca.e[3 + t] = {aout_W + (size_t)t * 512 * 512, aoutT + (size_t)t * 512 * 512, 512, 512, 8, 576 + 64 * t};
    ca.e[6]  = {mx_W1,    mx1T,   512,  1536, 8,  768};
    ca.e[7]  = {el_qkv_W, elqkvT, 1536, 512,  24, 960};
    ca.e[8]  = {el_out_W, eloutT, 512,  512,  8,  1152};
    ca.e[9]  = {el_ff_W1, ff1T,   2048, 512,  32, 1216};
    ca.e[10] = {el_ff_W2, ff2T,   512,  2048, 8,  1472};
    ca.e[11] = {op_W,     opT,    512,  512,  8,  1728};
    prep_all<<<1024 + 1792 + 18, 256, 0, stream>>>(x, XB, ca, enc_W, enc_b,
                                                   enc_ln_g, enc_ln_b, LUTB);
  }

  // 2. per-timescale masked attention (flash computes mask from LUT in-kernel)
  gemm_pipe<128,64,64><<<dim3(24, 16, 3), 256, 0, stream>>>(XB, 512, 0, qkvT, 512, (size_t)1536 * 512,
      qkv_b, 1536, nullptr, QKVb, 1536, (size_t)2048 * 1536, 512, 0);
  transpose_v<<<dim3(8, 32, 3), 256, 0, stream>>>(QKVb, (size_t)2048 * 1536, VTb, (size_t)32 * 64 * 512);
  flash_attn<true><<<dim3(8, 32, 3), 256, 0, stream>>>(QKVb, (size_t)2048 * 1536,
      VTb, (size_t)32 * 64 * 512, ts, LUTB, CTXb, (size_t)2048 * 512);
  gemm_pipe<64,32,128><<<dim3(16, 32, 3), 256, 0, stream>>>(CTXb, 512, (size_t)2048 * 512, aoutT, 512, (size_t)512 * 512,
      aout_b, 512, nullptr, COMBb, 1536, 512, 512, 0);

  // 3. time mixer (fused LN+gelu+mixer2+softmax+weighted)
  gemm_pipe<64,32,128><<<dim3(16, 32, 1), 256, 0, stream>>>(COMBb, 1536, 0, mx1T, 1536, 0,
      mx_b1, 0, MBUF, nullptr, 512, 0, 1536, 0);
  ln_mixer_weighted<<<512, 256, 0, stream>>>(MBUF, mx_ln_g, mx_ln_b, mx_W2, mx_b2, COMBb, WEI, WEIb);

  // 4. transformer encoder layer (post-norm)
  gemm_pipe<128,64,64><<<dim3(24, 16, 1), 256, 0, stream>>>(WEIb, 512, 0, elqkvT, 512, 0,
      el_qkv_b, 0, nullptr, QKVb, 1536, 0, 512, 0);
  transpose_v<<<dim3(8, 32, 1), 256, 0, stream>>>(QKVb, 0, VTb, 0);
  flash_attn<false><<<dim3(8, 32, 1), 256, 0, stream>>>(QKVb, 0, VTb, 0, nullptr, nullptr, CTXb, 0);
  gemm_pipe<64,32,128><<<dim3(16, 32, 1), 256, 0, stream>>>(CTXb, 512, 0, eloutT, 512, 0,
      el_out_b, 0, SA, nullptr, 512, 0, 512, 0);
  ln_rows<<<512, 256, 0, stream>>>(WEI, SA, el_ln1_g, el_ln1_b, H1, H1b, 0);
  gemm_pipe<128,64,64><<<dim3(32, 16, 1), 256, 0, stream>>>(H1b, 512, 0, ff1T, 512, 0,
      el_ff_b1, 0, nullptr, FFBb, 2048, 0, 512, 1);
  gemm_pipe<64,32,128><<<dim3(16, 32, 1), 256, 0, stream>>>(FFBb, 2048, 0, ff2T, 2048, 0,
      el_ff_b2, 0, SA, nullptr, 512, 0, 2048, 0);
  ln_rows<<<512, 256, 0, stream>>>(H1, SA, el_ln2_g, el_ln2_b, H2, H2b, 0);

  // 5. output projection + final LN
  gemm_pipe<64,32,128><<<dim3(16, 32, 1), 256, 0, stream>>>(H2b, 512, 0, opT, 512, 0,
      op_b, 0, OPO, nullptr, 512, 0, 512, 0);
  ln_rows<<<512, 256, 0, stream>>>(OPO, nullptr, op_ln_g, op_ln_b, (float*)d_out, nullptr, 0);
}

// Round 14
// 204.629 us; speedup vs baseline: 1.3561x; 1.3561x over previous
//
#include <hip/hip_runtime.h>
#include <hip/hip_bf16.h>
#include <math.h>

#define Bq 4
#define Sq 512
#define Hq 512
#define NHq 8
#define Tq 3
#define DTSq 170
#define BSq 2048
#define NLUT 2048
#define MAGMAXf 5.6304994f

typedef float f32x4 __attribute__((ext_vector_type(4)));
typedef __bf16 bf16x4 __attribute__((ext_vector_type(4)));
typedef __bf16 bf16x8 __attribute__((ext_vector_type(8)));

__device__ __forceinline__ float gelu_f(float x){
  return 0.5f * x * (1.0f + erff(x * 0.70710678118654752f));
}

__device__ __forceinline__ void gload16(const void* g, void* l){
  __builtin_amdgcn_global_load_lds((const __attribute__((address_space(1))) void*)g,
                                   (__attribute__((address_space(3))) void*)l, 16, 0, 0);
}

__device__ __forceinline__ float waveReduceSum(float v){
  #pragma unroll
  for (int off = 32; off > 0; off >>= 1) v += __shfl_xor(v, off);
  return v;
}

__device__ __forceinline__ float blockReduce(float v, float* red){
  int tid = threadIdx.x;
  __syncthreads();
  red[tid] = v; __syncthreads();
  for (int s = 128; s > 0; s >>= 1){
    if (tid < s) red[tid] += red[tid + s];
    __syncthreads();
  }
  return red[0];
}

// ---------------- merged prep: x->bf16 | weight T-convert | mask LUT --------
struct CvtEnt { const float* W; __bf16* WT; int ldw, ldt, ntn, start; };
struct CvtArgs { CvtEnt e[12]; };

__global__ __launch_bounds__(256) void prep_all(
    const float* __restrict__ x, __bf16* __restrict__ xb,
    CvtArgs a,
    const float* __restrict__ encW, const float* __restrict__ encB,
    const float* __restrict__ g, const float* __restrict__ be,
    float* __restrict__ lut)
{
  __shared__ float T[64][65];
  __shared__ float red[256];
  __shared__ float sw0[DTSq], sw1[DTSq], sbc[DTSq], sg[DTSq], sbe[DTSq];
  __shared__ float sS[6];
  int bid = blockIdx.x, tid = threadIdx.x;

  if (bid < 1024){                                  // cvt_bf: x -> XB
    int idx = (bid * 256 + tid) * 4;
    float4 v = *(const float4*)&x[idx];
    bf16x4 r; r[0]=(__bf16)v.x; r[1]=(__bf16)v.y; r[2]=(__bf16)v.z; r[3]=(__bf16)v.w;
    *(bf16x4*)&xb[idx] = r;
    return;
  }
  if (bid < 1024 + 1792){                           // weight transpose-convert
    int wb = bid - 1024;
    int i = 0;
    #pragma unroll
    for (int k = 1; k < 12; ++k) if (wb >= a.e[k].start) i = k;
    const float* W = a.e[i].W;
    __bf16* WT = a.e[i].WT;
    int ldw = a.e[i].ldw, ldt = a.e[i].ldt;
    int local = wb - a.e[i].start;
    int tn = local % a.e[i].ntn, tk = local / a.e[i].ntn;
    int n0 = tn * 64, k0 = tk * 64;
    #pragma unroll
    for (int q = 0; q < 16; ++q){
      int lin = q * 256 + tid;
      int r = lin >> 6, c = lin & 63;
      T[r][c] = W[(size_t)(k0 + r) * ldw + n0 + c];
    }
    __syncthreads();
    #pragma unroll
    for (int q = 0; q < 16; ++q){
      int lin = q * 256 + tid;
      int n = lin >> 6, k = lin & 63;
      WT[(size_t)(n0 + n) * ldt + k0 + k] = (__bf16)T[k][n];
    }
    return;
  }
  // mask LUT build (72 blocks): local = td*8 + echunk
  int local = bid - (1024 + 1792);
  int td = local >> 3, echunk = local & 7;
  int t = td / 3, dsel = td % 3;
  float d = (float)(dsel - 1);
  const float* W0 = encW + t * 2 * DTSq;
  const float* W1 = W0 + DTSq;
  const float* Bv = encB + t * DTSq;
  float w0 = (tid < DTSq) ? W0[tid] : 0.f;
  float w1 = (tid < DTSq) ? W1[tid] : 0.f;
  float bv = (tid < DTSq) ? Bv[tid] : 0.f;
  const float invD = 1.0f / (float)DTSq;
  float m0 = blockReduce(w0, red) * invD;
  float m1 = blockReduce(w1, red) * invD;
  float mb = blockReduce(bv, red) * invD;
  float c0 = (tid < DTSq) ? (w0 - m0) : 0.f;
  float c1 = (tid < DTSq) ? (w1 - m1) : 0.f;
  float cb = (tid < DTSq) ? (bv - mb) : 0.f;
  if (tid < DTSq){
    sw0[tid] = c0; sw1[tid] = c1; sbc[tid] = cb;
    sg[tid] = g[t * DTSq + tid]; sbe[tid] = be[t * DTSq + tid];
  }
  float pa = blockReduce(c0 * c0, red) * invD;
  float pb = blockReduce(c1 * c1, red) * invD;
  float pc = blockReduce(c0 * c1, red) * invD;
  float pd = blockReduce(c0 * cb, red) * invD;
  float pe = blockReduce(c1 * cb, red) * invD;
  float pf = blockReduce(cb * cb, red) * invD;
  if (tid == 0){ sS[0]=pa; sS[1]=pb; sS[2]=pc; sS[3]=pd; sS[4]=pe; sS[5]=pf; }
  __syncthreads();
  float A = sS[0], Bs = sS[1], Cs = sS[2], Ds = sS[3], Es = sS[4], Fs = sS[5];
  int e = echunk * 256 + tid;
  float tscale = (t == 0) ? 1.f : ((t == 1) ? 0.1f : 0.01f);
  float m = (MAGMAXf / (float)(NLUT - 1)) * (float)e * tscale;
  float var = fabsf(d) * A + m * m * Bs + Fs + 2.f * (d * m * Cs + d * Ds + m * Es);
  float rs = rsqrtf(var + 1e-5f);
  float sum = 0.f;
  for (int c = 0; c < DTSq; ++c){
    float ee = fmaf(m, sw1[c], fmaf(d, sw0[c], sbc[c]));
    float n = fmaf(ee * rs, sg[c], sbe[c]);
    sum += n * 0.5f * (1.0f + erff(n * 0.70710678118654752f));
  }
  lut[td * NLUT + e] = sum * (1.0f / (float)DTSq);
}

// ------- merged: mask fill (2048 blocks) + V transpose (768 blocks) ----------
__global__ __launch_bounds__(256) void mask_transpose(
    const float* __restrict__ ts, const float* __restrict__ lut,
    __bf16* __restrict__ maskbuf,
    const __bf16* __restrict__ qkv, size_t sQz,
    __bf16* __restrict__ vt, size_t sVz)
{
  __shared__ __bf16 T[64][72];
  int bid = blockIdx.x, tid = threadIdx.x;
  if (bid < BSq){
    // mask fill via LUT interpolation
    int b = bid >> 9, i = bid & 511;
    float tsi = ts[bid];
    for (int j0 = 0; j0 < Sq; j0 += 256){
      int j = j0 + tid;
      float dt = tsi - ts[(b << 9) + j];
      int dsel = (dt > 0.f) ? 2 : ((dt < 0.f) ? 0 : 1);
      float mag = log1pf(fabsf(dt) * (1.0f / 3600.0f));
      float u = mag * ((float)(NLUT - 1) / MAGMAXf);
      int i0 = (int)u; if (i0 > NLUT - 2) i0 = NLUT - 2;
      float f = u - (float)i0;
      #pragma unroll
      for (int t = 0; t < Tq; ++t){
        const float* lp = lut + (t * 3 + dsel) * NLUT + i0;
        float v = lp[0] + f * (lp[1] - lp[0]);
        maskbuf[(((size_t)(t * Bq + b) * Sq + i) * Sq) + j] = (__bf16)v;
      }
    }
    return;
  }
  // V transpose: local = t*256 + bh*8 + so_tile
  int local = bid - BSq;
  int t = local >> 8;
  int r = local & 255;
  int bh = r >> 3, b = bh >> 3, h = bh & 7;
  int so = (r & 7) * 64;
  const __bf16* q = qkv + (size_t)t * sQz;
  __bf16* v = vt + (size_t)t * sVz;
  #pragma unroll
  for (int qq = 0; qq < 16; ++qq){
    int lin = qq * 256 + tid;
    int rr = lin >> 6, c = lin & 63;
    T[rr][c] = q[(size_t)(b * Sq + so + rr) * 1536 + 1024 + h * 64 + c];
  }
  __syncthreads();
  #pragma unroll
  for (int qq = 0; qq < 16; ++qq){
    int lin = qq * 256 + tid;
    int d = lin >> 6, s = lin & 63;
    v[((size_t)bh * 64 + d) * Sq + so + s] = T[s][d];
  }
}

// ------ pipelined bf16 MFMA GEMM (counted vmcnt, 2 barriers; BK templated) ---
template<int BM, int BN, int BK>
__global__ __launch_bounds__(256) void gemm_pipe(
    const __bf16* __restrict__ A, int lda, size_t sAz,
    const __bf16* __restrict__ BT, int ldb, size_t sBz,
    const float* __restrict__ bias, int sBiasz,
    float* __restrict__ C32, __bf16* __restrict__ C16, int ldc, size_t sCz,
    int K, int act)
{
  constexpr int MF = BM / 32;
  constexpr int NF = BN / 32;
  constexpr int ROWB = BK * 2;                 // bytes per LDS row
  constexpr int SWZM = (BK == 64) ? 7 : 15;    // swizzle row mask
  constexpr int ALOADS = BM * ROWB / 4096;
  constexpr int BLOADS = BN * ROWB / 4096;
  constexpr int LOADS = ALOADS + BLOADS;
  constexpr int ABYTES = BM * ROWB;
  constexpr int BBYTES = BN * ROWB;
  __shared__ __bf16 lds[(2 * (ABYTES + BBYTES)) / 2];
  int tid = threadIdx.x;

  int gx = gridDim.x, nwg = gx * gridDim.y;
  int lin = blockIdx.x + gx * blockIdx.y;
  int q8 = nwg >> 3;
  int swz = (lin & 7) * q8 + (lin >> 3);
  int bx = swz % gx, by = swz / gx;

  int z = blockIdx.z;
  A  += (size_t)z * sAz;
  BT += (size_t)z * sBz;
  const float* bz = bias ? bias + (size_t)z * sBiasz : nullptr;
  size_t cbase = (size_t)z * sCz;
  int brow = by * BM, bcol = bx * BN;

  int lane = tid & 63, w = tid >> 6;
  int wr = (w >> 1) * (BM / 2), wc = (w & 1) * (BN / 2);
  int lr = lane & 15, lg = lane >> 4;

  f32x4 acc[MF][NF];
  #pragma unroll
  for (int m = 0; m < MF; ++m)
    #pragma unroll
    for (int n = 0; n < NF; ++n) acc[m][n] = (f32x4){0.f, 0.f, 0.f, 0.f};

  char* lbase = (char*)lds;

  auto stage = [&](int buf, int ko){
    char* ab = lbase + buf * (ABYTES + BBYTES);
    #pragma unroll
    for (int qq = 0; qq < ALOADS; ++qq){
      int byte = (qq * 256 + tid) * 16;
      int row = byte / ROWB, col = byte % ROWB;
      int src = col ^ ((row & SWZM) << 4);
      gload16(&A[(size_t)(brow + row) * lda + ko + (src >> 1)], ab + byte);
    }
    char* bb = ab + ABYTES;
    #pragma unroll
    for (int qq = 0; qq < BLOADS; ++qq){
      int byte = (qq * 256 + tid) * 16;
      int row = byte / ROWB, col = byte % ROWB;
      int src = col ^ ((row & SWZM) << 4);
      gload16(&BT[(size_t)(bcol + row) * ldb + ko + (src >> 1)], bb + byte);
    }
  };

  stage(0, 0);
  int nk = K / BK;
  for (int kt = 0; kt < nk; ++kt){
    int cur = kt & 1;
    if (kt + 1 < nk){
      stage(cur ^ 1, (kt + 1) * BK);
      if constexpr (LOADS == 3)      asm volatile("s_waitcnt vmcnt(3)" ::: "memory");
      else if constexpr (LOADS == 4) asm volatile("s_waitcnt vmcnt(4)" ::: "memory");
      else                           asm volatile("s_waitcnt vmcnt(6)" ::: "memory");
    } else {
      asm volatile("s_waitcnt vmcnt(0)" ::: "memory");
    }
    __builtin_amdgcn_s_barrier();
    __builtin_amdgcn_sched_barrier(0);
    char* ab = lbase + cur * (ABYTES + BBYTES);
    char* bb = ab + ABYTES;
    #pragma unroll
    for (int s = 0; s < BK / 32; ++s){
      bf16x8 af[MF], bfr[NF];
      #pragma unroll
      for (int m = 0; m < MF; ++m){
        int row = wr + m * 16 + lr;
        int col = (s * 64 + lg * 16) ^ ((row & SWZM) << 4);
        af[m] = *(const bf16x8*)(ab + row * ROWB + col);
      }
      #pragma unroll
      for (int n = 0; n < NF; ++n){
        int row = wc + n * 16 + lr;
        int col = (s * 64 + lg * 16) ^ ((row & SWZM) << 4);
        bfr[n] = *(const bf16x8*)(bb + row * ROWB + col);
      }
      #pragma unroll
      for (int m = 0; m < MF; ++m)
        #pragma unroll
        for (int n = 0; n < NF; ++n)
          acc[m][n] = __builtin_amdgcn_mfma_f32_16x16x32_bf16(af[m], bfr[n], acc[m][n], 0, 0, 0);
    }
    asm volatile("" ::: "memory");
    __builtin_amdgcn_s_barrier();
  }

  #pragma unroll
  for (int m = 0; m < MF; ++m){
    #pragma unroll
    for (int n = 0; n < NF; ++n){
      int col = bcol + wc + n * 16 + lr;
      float bv = bz ? bz[col] : 0.f;
      #pragma unroll
      for (int j = 0; j < 4; ++j){
        int row = brow + wr + m * 16 + lg * 4 + j;
        float v = acc[m][n][j] + bv;
        if (act) v = gelu_f(v);
        size_t idx = cbase + (size_t)row * ldc + col;
        if (C32) C32[idx] = v;
        if (C16) C16[idx] = (__bf16)v;
      }
    }
  }
}

// ---------------- flash attention v3 (r12): K/V/mask via global_load_lds -----
template<bool HM>
__global__ __launch_bounds__(256) void flash_attn(
    const __bf16* __restrict__ qkv, size_t sQz,   // [2048][1536]
    const __bf16* __restrict__ vt,  size_t sVz,   // [32][64][512]
    const __bf16* __restrict__ mask, size_t sMz,  // [4][512][512] bf16
    __bf16* __restrict__ ctx, size_t sCz)         // [2048][512]
{
  int t = blockIdx.z;
  qkv += (size_t)t * sQz;
  vt  += (size_t)t * sVz;
  ctx += (size_t)t * sCz;
  const __bf16* mk = HM ? mask + (size_t)t * sMz : nullptr;

  int lin = blockIdx.x + (blockIdx.y << 3);
  int swz = (lin & 7) * 32 + (lin >> 3);
  int io = (swz & 7) * 64;
  int bh = swz >> 3;
  int b = bh >> 3, h = bh & 7;

  constexpr int TB = 8192;
  constexpr int BUFB = HM ? 3 * TB : 2 * TB;
  __shared__ char lds[2 * BUFB + (HM ? 0 : TB)];
  char* lb = lds;
  int tid = threadIdx.x, lane = tid & 63, w = tid >> 6;
  int lr = lane & 15, lg = lane >> 4;

  const __bf16* qrow = &qkv[(size_t)(b * Sq + io + w * 16 + lr) * 1536 + h * 64];
  bf16x8 q0 = *(const bf16x8*)&qrow[lg * 8];
  bf16x8 q1 = *(const bf16x8*)&qrow[32 + lg * 8];

  auto stage = [&](int buf, int jo){
    char* kb = lb + buf * BUFB;
    #pragma unroll
    for (int qq = 0; qq < 2; ++qq){
      int byte = (qq * 256 + tid) * 16;
      int row = byte >> 7;
      int src = (byte & 127) ^ ((row & 7) << 4);
      gload16(&qkv[(size_t)(b * Sq + jo + row) * 1536 + 512 + h * 64 + (src >> 1)], kb + byte);
    }
    char* vb = kb + TB;
    #pragma unroll
    for (int qq = 0; qq < 2; ++qq){
      int byte = (qq * 256 + tid) * 16;
      int row = byte >> 7;
      int src = (byte & 127) ^ ((row & 7) << 4);
      gload16(&vt[((size_t)bh * 64 + row) * Sq + jo + (src >> 1)], vb + byte);
    }
    if constexpr (HM){
      char* mb = vb + TB;
      #pragma unroll
      for (int qq = 0; qq < 2; ++qq){
        int byte = (qq * 256 + tid) * 16;
        int row = byte >> 7;
        int src = (byte & 127) ^ ((row & 7) << 4);
        gload16(&mk[(size_t)(b * Sq + io + row) * Sq + jo + (src >> 1)], mb + byte);
      }
    }
  };

  f32x4 o[4];
  #pragma unroll
  for (int n = 0; n < 4; ++n) o[n] = (f32x4){0.f, 0.f, 0.f, 0.f};
  float mrow[4] = {-1e30f, -1e30f, -1e30f, -1e30f};
  float lrow[4] = {0.f, 0.f, 0.f, 0.f};

  stage(0, 0);
  #pragma unroll
  for (int kt = 0; kt < 8; ++kt){
    int cur = kt & 1;

    if (kt + 1 < 8){
      stage(cur ^ 1, (kt + 1) << 6);
      if constexpr (HM) asm volatile("s_waitcnt vmcnt(6)" ::: "memory");
      else              asm volatile("s_waitcnt vmcnt(4)" ::: "memory");
    } else {
      asm volatile("s_waitcnt vmcnt(0)" ::: "memory");
    }
    __builtin_amdgcn_s_barrier();
    __builtin_amdgcn_sched_barrier(0);

    char* kb = lb + cur * BUFB;
    char* vb = kb + TB;
    char* mb = HM ? vb + TB : lb + 2 * BUFB;

    // QK^T
    f32x4 s4[4];
    #pragma unroll
    for (int n = 0; n < 4; ++n) s4[n] = (f32x4){0.f, 0.f, 0.f, 0.f};
    __builtin_amdgcn_s_setprio(1);
    #pragma unroll
    for (int s = 0; s < 2; ++s){
      bf16x8 aq = s ? q1 : q0;
      #pragma unroll
      for (int n = 0; n < 4; ++n){
        int row = n * 16 + lr;
        int colb = (s * 64 + lg * 16) ^ ((row & 7) << 4);
        bf16x8 bk = *(const bf16x8*)(kb + row * 128 + colb);
        s4[n] = __builtin_amdgcn_mfma_f32_16x16x32_bf16(aq, bk, s4[n], 0, 0, 0);
      }
    }
    __builtin_amdgcn_s_setprio(0);

    float sv[4][4];
    #pragma unroll
    for (int n = 0; n < 4; ++n){
      #pragma unroll
      for (int reg = 0; reg < 4; ++reg){
        float v = s4[n][reg] * 0.125f;
        if constexpr (HM){
          int row = w * 16 + lg * 4 + reg;
          int off = ((n * 16 + lr) * 2) ^ ((row & 7) << 4);
          v += (float)*(const __bf16*)(mb + row * 128 + off);
        }
        sv[n][reg] = v;
      }
    }

    // online softmax with defer-max (THR=8)
    #pragma unroll
    for (int reg = 0; reg < 4; ++reg){
      float pmax = fmaxf(fmaxf(sv[0][reg], sv[1][reg]), fmaxf(sv[2][reg], sv[3][reg]));
      #pragma unroll
      for (int off = 1; off < 16; off <<= 1) pmax = fmaxf(pmax, __shfl_xor(pmax, off));
      if (pmax > mrow[reg] + 8.0f){
        float corr = __expf(mrow[reg] - pmax);
        mrow[reg] = pmax;
        lrow[reg] *= corr;
        #pragma unroll
        for (int n = 0; n < 4; ++n) o[n][reg] *= corr;
      }
      float rs = 0.f;
      #pragma unroll
      for (int n = 0; n < 4; ++n){
        float p = __expf(sv[n][reg] - mrow[reg]);
        sv[n][reg] = p;
        rs += p;
      }
      #pragma unroll
      for (int off = 1; off < 16; off <<= 1) rs += __shfl_xor(rs, off);
      lrow[reg] += rs;
    }

    // P -> Ps (aliases cur mask buf for HM; per-wave 16-row slice), then PV
    #pragma unroll
    for (int n = 0; n < 4; ++n)
      #pragma unroll
      for (int reg = 0; reg < 4; ++reg){
        int row = w * 16 + lg * 4 + reg;
        int off = ((n * 16 + lr) * 2) ^ ((row & 7) << 4);
        *(__bf16*)(mb + row * 128 + off) = (__bf16)sv[n][reg];
      }
    __builtin_amdgcn_s_setprio(1);
    #pragma unroll
    for (int s = 0; s < 2; ++s){
      int arow = w * 16 + lr;
      int acol = (s * 64 + lg * 16) ^ ((arow & 7) << 4);
      bf16x8 ap = *(const bf16x8*)(mb + arow * 128 + acol);
      #pragma unroll
      for (int n = 0; n < 4; ++n){
        int row = n * 16 + lr;
        int colb = (s * 64 + lg * 16) ^ ((row & 7) << 4);
        bf16x8 bv = *(const bf16x8*)(vb + row * 128 + colb);
        o[n] = __builtin_amdgcn_mfma_f32_16x16x32_bf16(ap, bv, o[n], 0, 0, 0);
      }
    }
    __builtin_amdgcn_s_setprio(0);

    asm volatile("" ::: "memory");
    __builtin_amdgcn_s_barrier();
  }

  #pragma unroll
  for (int reg = 0; reg < 4; ++reg){
    float inv = 1.0f / lrow[reg];
    int row = b * Sq + io + w * 16 + lg * 4 + reg;
    #pragma unroll
    for (int n = 0; n < 4; ++n)
      ctx[(size_t)row * Hq + h * 64 + n * 16 + lr] = (__bf16)(o[n][reg] * inv);
  }
}

// ---------------- row LayerNorm (+residual), dual-dtype out ------------------
__global__ __launch_bounds__(256) void ln_rows(const float* __restrict__ in,
                                               const float* __restrict__ res,
                                               const float* __restrict__ g,
                                               const float* __restrict__ bb,
                                               float* __restrict__ out32,
                                               __bf16* __restrict__ out16,
                                               int do_gelu){
  int row = blockIdx.x * 4 + (threadIdx.x >> 6);
  int lane = threadIdx.x & 63;
  const float* ir = in + (size_t)row * Hq;
  const float* rr = res ? res + (size_t)row * Hq : nullptr;
  float x[8]; float s = 0.f, sq = 0.f;
  #pragma unroll
  for (int k = 0; k < 8; ++k){
    int c = lane + 64 * k;
    float v = ir[c];
    if (rr) v += rr[c];
    x[k] = v; s += v; sq += v * v;
  }
  s = waveReduceSum(s); sq = waveReduceSum(sq);
  float mean = s * (1.0f / Hq);
  float var = fmaxf(sq * (1.0f / Hq) - mean * mean, 0.f);
  float rstd = rsqrtf(var + 1e-5f);
  #pragma unroll
  for (int k = 0; k < 8; ++k){
    int c = lane + 64 * k;
    float y = (x[k] - mean) * rstd * g[c] + bb[c];
    if (do_gelu) y = gelu_f(y);
    if (out32) out32[(size_t)row * Hq + c] = y;
    if (out16) out16[(size_t)row * Hq + c] = (__bf16)y;
  }
}

// ------- fused: LN + gelu + mixer2 + softmax over T + weighted combine -------
__global__ __launch_bounds__(256) void ln_mixer_weighted(const float* __restrict__ in,
                                                         const float* __restrict__ g,
                                                         const float* __restrict__ bb,
                                                         const float* __restrict__ W2,
                                                         const float* __restrict__ b2,
                                                         const __bf16* __restrict__ comb,
                                                         float* __restrict__ out32,
                                                         __bf16* __restrict__ out16){
  int row = blockIdx.x * 4 + (threadIdx.x >> 6);
  int lane = threadIdx.x & 63;
  const float* ir = in + (size_t)row * Hq;
  float x[8]; float s = 0.f, sq = 0.f;
  #pragma unroll
  for (int k = 0; k < 8; ++k){
    int c = lane + 64 * k;
    float v = ir[c];
    x[k] = v; s += v; sq += v * v;
  }
  s = waveReduceSum(s); sq = waveReduceSum(sq);
  float mean = s * (1.0f / Hq);
  float var = fmaxf(sq * (1.0f / Hq) - mean * mean, 0.f);
  float rstd = rsqrtf(var + 1e-5f);
  float a0 = 0.f, a1 = 0.f, a2 = 0.f;
  #pragma unroll
  for (int k = 0; k < 8; ++k){
    int c = lane + 64 * k;
    float y = gelu_f((x[k] - mean) * rstd * g[c] + bb[c]);
    const float* wv = W2 + c * 3;
    a0 = fmaf(y, wv[0], a0); a1 = fmaf(y, wv[1], a1); a2 = fmaf(y, wv[2], a2);
  }
  a0 = waveReduceSum(a0) + b2[0];
  a1 = waveReduceSum(a1) + b2[1];
  a2 = waveReduceSum(a2) + b2[2];
  float mx = fmaxf(a0, fmaxf(a1, a2));
  float e0 = __expf(a0 - mx), e1 = __expf(a1 - mx), e2 = __expf(a2 - mx);
  float inv = 1.0f / (e0 + e1 + e2);
  float m0 = e0 * inv, m1 = e1 * inv, m2 = e2 * inv;
  const __bf16* cr = comb + (size_t)row * 1536;
  #pragma unroll
  for (int k = 0; k < 8; ++k){
    int c = lane + 64 * k;
    float v = m0 * (float)cr[c] + m1 * (float)cr[512 + c] + m2 * (float)cr[1024 + c];
    out32[(size_t)row * Hq + c] = v;
    out16[(size_t)row * Hq + c] = (__bf16)v;
  }
}

// ---------------- V transpose per head (el layer, z=1) -----------------------
__global__ __launch_bounds__(256) void transpose_v(const __bf16* __restrict__ qkv, size_t sQz,
                                                   __bf16* __restrict__ vt, size_t sVz){
  int t = blockIdx.z;
  qkv += (size_t)t * sQz;
  vt  += (size_t)t * sVz;
  int bh = blockIdx.y, b = bh >> 3, h = bh & 7;
  int so = blockIdx.x * 64;
  __shared__ __bf16 T[64][72];
  int tid = threadIdx.x;
  #pragma unroll
  for (int q = 0; q < 16; ++q){
    int lin = q * 256 + tid;
    int r = lin >> 6, c = lin & 63;
    T[r][c] = qkv[(size_t)(b * Sq + so + r) * 1536 + 1024 + h * 64 + c];
  }
  __syncthreads();
  #pragma unroll
  for (int q = 0; q < 16; ++q){
    int lin = q * 256 + tid;
    int d = lin >> 6, s = lin & 63;
    vt[((size_t)bh * 64 + d) * Sq + so + s] = T[s][d];
  }
}

extern "C" void kernel_launch(void* const* d_in, const int* in_sizes, int n_in,
                              void* d_out, int out_size, void* d_ws, size_t ws_size,
                              hipStream_t stream){
  const float* x         = (const float*)d_in[0];
  const float* ts        = (const float*)d_in[1];
  const float* enc_W     = (const float*)d_in[2];
  const float* enc_b     = (const float*)d_in[3];
  const float* enc_ln_g  = (const float*)d_in[4];
  const float* enc_ln_b  = (const float*)d_in[5];
  const float* qkv_W     = (const float*)d_in[6];
  const float* qkv_b     = (const float*)d_in[7];
  const float* aout_W    = (const float*)d_in[8];
  const float* aout_b    = (const float*)d_in[9];
  const float* mx_W1     = (const float*)d_in[10];
  const float* mx_b1     = (const float*)d_in[11];
  const float* mx_ln_g   = (const float*)d_in[12];
  const float* mx_ln_b   = (const float*)d_in[13];
  const float* mx_W2     = (const float*)d_in[14];
  const float* mx_b2     = (const float*)d_in[15];
  const float* el_qkv_W  = (const float*)d_in[16];
  const float* el_qkv_b  = (const float*)d_in[17];
  const float* el_out_W  = (const float*)d_in[18];
  const float* el_out_b  = (const float*)d_in[19];
  const float* el_ln1_g  = (const float*)d_in[20];
  const float* el_ln1_b  = (const float*)d_in[21];
  const float* el_ff_W1  = (const float*)d_in[22];
  const float* el_ff_b1  = (const float*)d_in[23];
  const float* el_ff_W2  = (const float*)d_in[24];
  const float* el_ff_b2  = (const float*)d_in[25];
  const float* el_ln2_g  = (const float*)d_in[26];
  const float* el_ln2_b  = (const float*)d_in[27];
  const float* op_W      = (const float*)d_in[28];
  const float* op_b      = (const float*)d_in[29];
  const float* op_ln_g   = (const float*)d_in[30];
  const float* op_ln_b   = (const float*)d_in[31];

  float* ws = (float*)d_ws;
  size_t o = 0;
  __bf16* MASKBb = (__bf16*)(ws + o); o += 1572864;           // [3][4][512][512]
  __bf16* XB     = (__bf16*)(ws + o); o += 524288;            // [2048][512]
  __bf16* qkvT   = (__bf16*)(ws + o); o += 1179648;           // [3][1536][512]
  __bf16* aoutT  = (__bf16*)(ws + o); o += 393216;            // [3][512][512]
  __bf16* mx1T   = (__bf16*)(ws + o); o += 393216;            // [512][1536]
  __bf16* elqkvT = (__bf16*)(ws + o); o += 393216;            // [1536][512]
  __bf16* eloutT = (__bf16*)(ws + o); o += 131072;            // [512][512]
  __bf16* ff1T   = (__bf16*)(ws + o); o += 524288;            // [2048][512]
  __bf16* ff2T   = (__bf16*)(ws + o); o += 524288;            // [512][2048]
  __bf16* opT    = (__bf16*)(ws + o); o += 131072;            // [512][512]
  __bf16* QKVb   = (__bf16*)(ws + o); o += 4718592;           // [3][2048][1536]
  __bf16* VTb    = (__bf16*)(ws + o); o += 1572864;           // [3][32][64][512]
  __bf16* FFBb   = (__bf16*)(ws + o); o += 2097152;           // [2048][2048]
  __bf16* CTXb   = (__bf16*)(ws + o); o += 1572864;           // [3][2048][512]
  __bf16* COMBb  = (__bf16*)(ws + o); o += 1572864;           // [2048][1536]
  float*  MBUF   = ws + o;            o += 1048576;           // mixer1 out, also OPO
  float*  WEI    = ws + o;            o += 1048576;
  __bf16* WEIb   = (__bf16*)(ws + o); o += 524288;
  float*  SA     = ws + o;            o += 1048576;
  float*  H1     = ws + o;            o += 1048576;
  __bf16* H1b    = (__bf16*)(ws + o); o += 524288;
  float*  H2     = ws + o;            o += 1048576;
  __bf16* H2b    = (__bf16*)(ws + o); o += 524288;
  float*  LUTB   = ws + o;            o += 9 * NLUT;
  float*  OPO    = MBUF;

  // 0+1. merged prep: x->bf16, weight transposes, mask LUT
  {
    CvtArgs ca;
    for (int t = 0; t < 3; ++t)
      ca.e[t] = {qkv_W + (size_t)t * 512 * 1536, qkvT + (size_t)t * 1536 * 512, 1536, 512, 24, 192 * t};
    for (int t = 0; t < 3; ++t)
      ca.e[3 + t] = {aout_W + (size_t)t * 512 * 512, aoutT + (size_t)t * 512 * 512, 512, 512, 8, 576 + 64 * t};
    ca.e[6]  = {mx_W1,    mx1T,   512,  1536, 8,  768};
    ca.e[7]  = {el_qkv_W, elqkvT, 1536, 512,  24, 960};
    ca.e[8]  = {el_out_W, eloutT, 512,  512,  8,  1152};
    ca.e[9]  = {el_ff_W1, ff1T,   2048, 512,  32, 1216};
    ca.e[10] = {el_ff_W2, ff2T,   512,  2048, 8,  1472};
    ca.e[11] = {op_W,     opT,    512,  512,  8,  1728};
    prep_all<<<1024 + 1792 + 72, 256, 0, stream>>>(x, XB, ca, enc_W, enc_b,
                                                   enc_ln_g, enc_ln_b, LUTB);
  }

  // 2. per-timescale masked attention (flash, t-batched)
  gemm_pipe<128,64,64><<<dim3(24, 16, 3), 256, 0, stream>>>(XB, 512, 0, qkvT, 512, (size_t)1536 * 512,
      qkv_b, 1536, nullptr, QKVb, 1536, (size_t)2048 * 1536, 512, 0);
  mask_transpose<<<BSq + 768, 256, 0, stream>>>(ts, LUTB, MASKBb,
      QKVb, (size_t)2048 * 1536, VTb, (size_t)32 * 64 * 512);
  flash_attn<true><<<dim3(8, 32, 3), 256, 0, stream>>>(QKVb, (size_t)2048 * 1536,
      VTb, (size_t)32 * 64 * 512, MASKBb, (size_t)4 * 512 * 512, CTXb, (size_t)2048 * 512);
  gemm_pipe<64,32,128><<<dim3(16, 32, 3), 256, 0, stream>>>(CTXb, 512, (size_t)2048 * 512, aoutT, 512, (size_t)512 * 512,
      aout_b, 512, nullptr, COMBb, 1536, 512, 512, 0);

  // 3. time mixer (fused LN+gelu+mixer2+softmax+weighted)
  gemm_pipe<64,32,128><<<dim3(16, 32, 1), 256, 0, stream>>>(COMBb, 1536, 0, mx1T, 1536, 0,
      mx_b1, 0, MBUF, nullptr, 512, 0, 1536, 0);
  ln_mixer_weighted<<<512, 256, 0, stream>>>(MBUF, mx_ln_g, mx_ln_b, mx_W2, mx_b2, COMBb, WEI, WEIb);

  // 4. transformer encoder layer (post-norm)
  gemm_pipe<128,64,64><<<dim3(24, 16, 1), 256, 0, stream>>>(WEIb, 512, 0, elqkvT, 512, 0,
      el_qkv_b, 0, nullptr, QKVb, 1536, 0, 512, 0);
  transpose_v<<<dim3(8, 32, 1), 256, 0, stream>>>(QKVb, 0, VTb, 0);
  flash_attn<false><<<dim3(8, 32, 1), 256, 0, stream>>>(QKVb, 0, VTb, 0, nullptr, 0, CTXb, 0);
  gemm_pipe<64,32,128><<<dim3(16, 32, 1), 256, 0, stream>>>(CTXb, 512, 0, eloutT, 512, 0,
      el_out_b, 0, SA, nullptr, 512, 0, 512, 0);
  ln_rows<<<512, 256, 0, stream>>>(WEI, SA, el_ln1_g, el_ln1_b, H1, H1b, 0);
  gemm_pipe<128,64,64><<<dim3(32, 16, 1), 256, 0, stream>>>(H1b, 512, 0, ff1T, 512, 0,
      el_ff_b1, 0, nullptr, FFBb, 2048, 0, 512, 1);
  gemm_pipe<64,32,128><<<dim3(16, 32, 1), 256, 0, stream>>>(FFBb, 2048, 0, ff2T, 2048, 0,
      el_ff_b2, 0, SA, nullptr, 512, 0, 2048, 0);
  ln_rows<<<512, 256, 0, stream>>>(H1, SA, el_ln2_g, el_ln2_b, H2, H2b, 0);

  // 5. output projection + final LN
  gemm_pipe<64,32,128><<<dim3(16, 32, 1), 256, 0, stream>>>(H2b, 512, 0, opT, 512, 0,
      op_b, 0, OPO, nullptr, 512, 0, 512, 0);
  ln_rows<<<512, 256, 0, stream>>>(OPO, nullptr, op_ln_g, op_ln_b, (float*)d_out, nullptr, 0);
}